// Round 3
// baseline (38.031 us; speedup 1.0000x reference)
//
#include <hip/hip_runtime.h>

#define BB 4
#define SS 4096
#define EE 128
#define KDD 64
#define NROWS (BB*SS)   // 16384

// ---------------------------------------------------------------------------
// Kernel A:
//  blocks [0,512):   query tile 32x64: query[bx*32 .. +31][0:64] = x @ Wq^T,
//                    plus xpart[bx][c] = column sums of the 32 x-rows
//                    (zeroed for the first two blocks of each batch: rows s<64)
//  blocks [512,524): idx=bx-512, b=idx/3, role=idx%3 on x[b,0:64] (64x64 tile):
//    role 0: value64[b][t][0:64]   = x64 @ Wv[0:64]^T
//    role 1: value64[b][t][64:128] = x64 @ Wv[64:128]^T
//    role 2: key64T[b][k][t] = (t<=k) ? x64[t].Wk[k] : 0
// ---------------------------------------------------------------------------
__global__ __launch_bounds__(256, 2)
void fused_a(const float* __restrict__ x, const float* __restrict__ Wq,
             const float* __restrict__ Wk, const float* __restrict__ Wv,
             float* __restrict__ query, float* __restrict__ value64,
             float* __restrict__ key64T, float* __restrict__ xpart)
{
    __shared__ float xs[64][132];
    __shared__ float wst[128][68];
    const int tid = threadIdx.x;
    const int bx = blockIdx.x;

    if (bx < 512) {
        // ---------------- query path: 32 rows x 64 cols ----------------
        const int xrow0 = bx * 32;
        #pragma unroll
        for (int i = 0; i < 4; ++i) {               // stage 32x128 x tile
            int f4 = tid + i * 256;
            int row = f4 >> 5, kq = f4 & 31;
            float4 v = *reinterpret_cast<const float4*>(x + (size_t)(xrow0 + row) * EE + 4 * kq);
            *reinterpret_cast<float4*>(&xs[row][4 * kq]) = v;
        }
        #pragma unroll
        for (int i = 0; i < 8; ++i) {               // stage Wq (64 rows) transposed
            int f4 = tid + i * 256;
            int c = f4 & 63, kq = f4 >> 6;
            float4 v = *reinterpret_cast<const float4*>(Wq + (size_t)c * EE + 4 * kq);
            wst[4 * kq + 0][c] = v.x;
            wst[4 * kq + 1][c] = v.y;
            wst[4 * kq + 2][c] = v.z;
            wst[4 * kq + 3][c] = v.w;
        }
        __syncthreads();

        const int ct = tid & 15, rt = tid >> 4;
        const int c0 = 4 * ct, r0 = 2 * rt;
        float acc[2][4] = {};
        #pragma unroll 4
        for (int k0 = 0; k0 < 128; k0 += 4) {
            float4 a[2], bq[4];
            #pragma unroll
            for (int i = 0; i < 2; ++i) a[i] = *reinterpret_cast<const float4*>(&xs[r0 + i][k0]);
            #pragma unroll
            for (int kk = 0; kk < 4; ++kk) bq[kk] = *reinterpret_cast<const float4*>(&wst[k0 + kk][c0]);
            #pragma unroll
            for (int i = 0; i < 2; ++i) {
                const float4 ai = a[i];
                acc[i][0] = fmaf(ai.x, bq[0].x, acc[i][0]);
                acc[i][1] = fmaf(ai.x, bq[0].y, acc[i][1]);
                acc[i][2] = fmaf(ai.x, bq[0].z, acc[i][2]);
                acc[i][3] = fmaf(ai.x, bq[0].w, acc[i][3]);
                acc[i][0] = fmaf(ai.y, bq[1].x, acc[i][0]);
                acc[i][1] = fmaf(ai.y, bq[1].y, acc[i][1]);
                acc[i][2] = fmaf(ai.y, bq[1].z, acc[i][2]);
                acc[i][3] = fmaf(ai.y, bq[1].w, acc[i][3]);
                acc[i][0] = fmaf(ai.z, bq[2].x, acc[i][0]);
                acc[i][1] = fmaf(ai.z, bq[2].y, acc[i][1]);
                acc[i][2] = fmaf(ai.z, bq[2].z, acc[i][2]);
                acc[i][3] = fmaf(ai.z, bq[2].w, acc[i][3]);
                acc[i][0] = fmaf(ai.w, bq[3].x, acc[i][0]);
                acc[i][1] = fmaf(ai.w, bq[3].y, acc[i][1]);
                acc[i][2] = fmaf(ai.w, bq[3].z, acc[i][2]);
                acc[i][3] = fmaf(ai.w, bq[3].w, acc[i][3]);
            }
        }
        #pragma unroll
        for (int i = 0; i < 2; ++i) {
            float4 o = make_float4(acc[i][0], acc[i][1], acc[i][2], acc[i][3]);
            *reinterpret_cast<float4*>(query + (size_t)(xrow0 + r0 + i) * KDD + c0) = o;
        }
        if (tid < 128) {            // x column partial sums for Vsum
            float s = 0.f;
            if ((bx & 127) >= 2) {  // first two blocks of batch cover s<64: excluded
                #pragma unroll 8
                for (int r = 0; r < 32; ++r) s += xs[r][tid];
            }
            xpart[(size_t)bx * 128 + tid] = s;
        }
    } else {
        // ---------------- special path: 64x64 tiles on x[b,0:64] ----------------
        const int idx = bx - 512;
        const int b = idx / 3, role = idx % 3;
        const int xrow0 = b * SS;
        const float* Wbase = (role == 0) ? Wv : (role == 1) ? (Wv + 64 * EE) : Wk;

        #pragma unroll
        for (int i = 0; i < 8; ++i) {
            int f4 = tid + i * 256;
            int row = f4 >> 5, kq = f4 & 31;
            float4 v = *reinterpret_cast<const float4*>(x + (size_t)(xrow0 + row) * EE + 4 * kq);
            *reinterpret_cast<float4*>(&xs[row][4 * kq]) = v;
        }
        #pragma unroll
        for (int i = 0; i < 8; ++i) {
            int f4 = tid + i * 256;
            int c = f4 & 63, kq = f4 >> 6;
            float4 v = *reinterpret_cast<const float4*>(Wbase + (size_t)c * EE + 4 * kq);
            wst[4 * kq + 0][c] = v.x;
            wst[4 * kq + 1][c] = v.y;
            wst[4 * kq + 2][c] = v.z;
            wst[4 * kq + 3][c] = v.w;
        }
        __syncthreads();

        const int ct = tid & 15, rt = tid >> 4;
        const int c0 = 4 * ct, r0 = 4 * rt;
        float acc[4][4] = {};
        #pragma unroll 4
        for (int k0 = 0; k0 < 128; k0 += 4) {
            float4 a[4], bq[4];
            #pragma unroll
            for (int i = 0; i < 4; ++i) a[i] = *reinterpret_cast<const float4*>(&xs[r0 + i][k0]);
            #pragma unroll
            for (int kk = 0; kk < 4; ++kk) bq[kk] = *reinterpret_cast<const float4*>(&wst[k0 + kk][c0]);
            #pragma unroll
            for (int i = 0; i < 4; ++i) {
                const float4 ai = a[i];
                acc[i][0] = fmaf(ai.x, bq[0].x, acc[i][0]);
                acc[i][1] = fmaf(ai.x, bq[0].y, acc[i][1]);
                acc[i][2] = fmaf(ai.x, bq[0].z, acc[i][2]);
                acc[i][3] = fmaf(ai.x, bq[0].w, acc[i][3]);
                acc[i][0] = fmaf(ai.y, bq[1].x, acc[i][0]);
                acc[i][1] = fmaf(ai.y, bq[1].y, acc[i][1]);
                acc[i][2] = fmaf(ai.y, bq[1].z, acc[i][2]);
                acc[i][3] = fmaf(ai.y, bq[1].w, acc[i][3]);
                acc[i][0] = fmaf(ai.z, bq[2].x, acc[i][0]);
                acc[i][1] = fmaf(ai.z, bq[2].y, acc[i][1]);
                acc[i][2] = fmaf(ai.z, bq[2].z, acc[i][2]);
                acc[i][3] = fmaf(ai.z, bq[2].w, acc[i][3]);
                acc[i][0] = fmaf(ai.w, bq[3].x, acc[i][0]);
                acc[i][1] = fmaf(ai.w, bq[3].y, acc[i][1]);
                acc[i][2] = fmaf(ai.w, bq[3].z, acc[i][2]);
                acc[i][3] = fmaf(ai.w, bq[3].w, acc[i][3]);
            }
        }

        if (role <= 1) {
            const int voff = role * 64 + c0;
            #pragma unroll
            for (int i = 0; i < 4; ++i) {
                float4 o = make_float4(acc[i][0], acc[i][1], acc[i][2], acc[i][3]);
                *reinterpret_cast<float4*>(value64 + ((size_t)b * 64 + r0 + i) * EE + voff) = o;
            }
        } else {
            #pragma unroll
            for (int i = 0; i < 4; ++i)
                #pragma unroll
                for (int j = 0; j < 4; ++j) {
                    const int t = r0 + i, k = c0 + j;
                    key64T[((size_t)b * 64 + k) * 64 + t] = (t <= k) ? acc[i][j] : 0.f;
                }
        }
    }
}

// ---------------------------------------------------------------------------
// Kernel C: vsum recompute (L2-resident) + 64 scores + softmax (incl. 4032
// zero cols) + PV. Grid (S/32, B); 4 waves, each owns 8 rows in one pass.
// All row-broadcasts via v_readlane (SALU) — no LDS broadcast traffic.
// ---------------------------------------------------------------------------
__device__ __forceinline__ float wave_max64(float v) {
    #pragma unroll
    for (int o = 32; o; o >>= 1) v = fmaxf(v, __shfl_xor(v, o));
    return v;
}
__device__ __forceinline__ float wave_sum64(float v) {
    #pragma unroll
    for (int o = 32; o; o >>= 1) v += __shfl_xor(v, o);
    return v;
}
__device__ __forceinline__ float lanebcast(float v, int l) {
    return __int_as_float(__builtin_amdgcn_readlane(__float_as_int(v), l));
}

__global__ __launch_bounds__(256, 2)
void attn_epilogue(const float* __restrict__ query, const float* __restrict__ value64,
                   const float* __restrict__ key64T, const float* __restrict__ xpart,
                   const float* __restrict__ Wv, float* __restrict__ out)
{
    __shared__ float Ks[64 * 64];    // [k][t] pre-masked
    __shared__ float Vl[64 * 128];   // [t][v]
    __shared__ float qs[32 * 64];    // [r][k]
    __shared__ float xsum[128];
    __shared__ float vs[128];
    const int tid = threadIdx.x;
    const int b = blockIdx.y;
    const int s0 = blockIdx.x * 32;

    #pragma unroll
    for (int i = 0; i < 4; ++i) {
        int f4 = tid + i * 256;
        *reinterpret_cast<float4*>(&Ks[4 * f4]) =
            *reinterpret_cast<const float4*>(key64T + (size_t)b * 64 * 64 + 4 * f4);
    }
    #pragma unroll
    for (int i = 0; i < 8; ++i) {
        int f4 = tid + i * 256;
        *reinterpret_cast<float4*>(&Vl[4 * f4]) =
            *reinterpret_cast<const float4*>(value64 + (size_t)b * 64 * EE + 4 * f4);
    }
    #pragma unroll
    for (int i = 0; i < 2; ++i) {
        int f4 = tid + i * 256;
        *reinterpret_cast<float4*>(&qs[4 * f4]) =
            *reinterpret_cast<const float4*>(query + ((size_t)b * SS + s0) * KDD + 4 * f4);
    }
    if (tid < 128) {                 // reduce xpart -> xsum (deterministic order)
        float s = 0.f;
        #pragma unroll 8
        for (int i = 0; i < 128; ++i) s += xpart[((size_t)b * 128 + i) * 128 + tid];
        xsum[tid] = s;
    }
    __syncthreads();
    if (tid < 128) {                 // vsum[v] = xsum . Wv[v]
        float acc = 0.f;
        #pragma unroll 8
        for (int e = 0; e < 128; e += 4) {
            float4 w = *reinterpret_cast<const float4*>(Wv + (size_t)tid * EE + e);
            acc = fmaf(xsum[e + 0], w.x, acc);
            acc = fmaf(xsum[e + 1], w.y, acc);
            acc = fmaf(xsum[e + 2], w.z, acc);
            acc = fmaf(xsum[e + 3], w.w, acc);
        }
        vs[tid] = acc;
    }
    __syncthreads();

    const int wave = tid >> 6, lane = tid & 63;
    const int rbase = wave * 8;

    float q[8], a[8];
    #pragma unroll
    for (int r = 0; r < 8; ++r) {
        q[r] = qs[(rbase + r) * 64 + lane];   // lane = k-dim
        a[r] = 0.f;
    }
    // QK: a[r] is the score for row (rbase+r), column t = lane
    #pragma unroll
    for (int k = 0; k < 64; ++k) {
        float kv = Ks[k * 64 + lane];
        #pragma unroll
        for (int r = 0; r < 8; ++r)
            a[r] = fmaf(lanebcast(q[r], k), kv, a[r]);
    }
    // softmax over 4096 cols: 64 real + 4032 exact zeros
    float w[8], e[8], iz[8];
    #pragma unroll
    for (int r = 0; r < 8; ++r) {
        float m = fmaxf(wave_max64(a[r]), 0.f);
        w[r] = __expf(a[r] - m);
        e[r] = __expf(-m);
        float z = wave_sum64(w[r]) + (float)(SS - 64) * e[r];
        iz[r] = 1.f / z;
    }
    // PV: lane owns output cols (2*lane, 2*lane+1)
    float ox[8] = {}, oy[8] = {};
    #pragma unroll
    for (int t = 0; t < 64; ++t) {
        float2 vv = *reinterpret_cast<const float2*>(&Vl[t * 128 + 2 * lane]);
        #pragma unroll
        for (int r = 0; r < 8; ++r) {
            float wt = lanebcast(w[r], t);
            ox[r] = fmaf(wt, vv.x, ox[r]);
            oy[r] = fmaf(wt, vv.y, oy[r]);
        }
    }
    float2 vsv = *reinterpret_cast<const float2*>(&vs[2 * lane]);
    #pragma unroll
    for (int r = 0; r < 8; ++r) {
        float2 o;
        o.x = (ox[r] + e[r] * vsv.x) * iz[r];
        o.y = (oy[r] + e[r] * vsv.y) * iz[r];
        *reinterpret_cast<float2*>(out + ((size_t)b * SS + s0 + rbase + r) * EE + 2 * lane) = o;
    }
}

// ---------------------------------------------------------------------------
extern "C" void kernel_launch(void* const* d_in, const int* in_sizes, int n_in,
                              void* d_out, int out_size, void* d_ws, size_t ws_size,
                              hipStream_t stream)
{
    const float* x  = (const float*)d_in[0];
    const float* Wk = (const float*)d_in[1];
    const float* Wq = (const float*)d_in[2];
    const float* Wv = (const float*)d_in[3];
    float* out = (float*)d_out;

    float* ws      = (float*)d_ws;
    float* query   = ws;                                    // NROWS*KDD
    float* value64 = query + (size_t)NROWS * KDD;           // BB*64*EE
    float* key64T  = value64 + (size_t)BB * 64 * EE;        // BB*64*64
    float* xpart   = key64T + (size_t)BB * 64 * 64;         // 512*128

    fused_a<<<524, 256, 0, stream>>>(x, Wq, Wk, Wv, query, value64, key64T, xpart);
    attn_epilogue<<<dim3(SS / 32, BB), 256, 0, stream>>>(query, value64, key64T, xpart, Wv, out);
}